// Round 15
// baseline (77.897 us; speedup 1.0000x reference)
//
#include <hip/hip_runtime.h>

#define DS   256
#define FULL 2048
#define NIMG 8
#define CG   4      // columns per k_colup block

typedef float f32x4 __attribute__((ext_vector_type(4)));
typedef int   i32x4 __attribute__((ext_vector_type(4)));

// Segment-mean contribution for a 256-long line handled by 256 threads.
// Returns lr+rl (or 2x where invalid), matching the reference _seg_means.
// Safe to call back-to-back (internal barriers cover the reuse hazards).
__device__ __forceinline__ float seg_fast(float x, bool z, int j,
                                          float* s_cs,
                                          unsigned long long* s_msk,
                                          float* s_ws) {
    const int lane = j & 63;
    const int w    = j >> 6;
    unsigned long long m = __ballot(z);

    float s = x;
    #pragma unroll
    for (int off = 1; off < 64; off <<= 1) {
        float t = __shfl_up(s, off, 64);
        if (lane >= off) s += t;
    }
    if (lane == 63) s_ws[w]  = s;
    if (lane == 0)  s_msk[w] = m;
    __syncthreads();

    float pre = 0.f;
    for (int ww = 0; ww < w; ++ww) pre += s_ws[ww];
    s += pre;
    s_cs[j] = s;

    unsigned long long lo = m & ((1ULL << lane) - 1ULL);
    int prev = -1;
    if (lo) prev = (w << 6) + 63 - __builtin_clzll(lo);
    else {
        for (int ww = w - 1; ww >= 0; --ww) {
            unsigned long long mm = s_msk[ww];
            if (mm) { prev = (ww << 6) + 63 - __builtin_clzll(mm); break; }
        }
    }
    unsigned long long hi = m & ~((2ULL << lane) - 1ULL);
    int nxt = DS;
    if (hi) nxt = (w << 6) + __builtin_ctzll(hi);
    else {
        for (int ww = w + 1; ww < 4; ++ww) {
            unsigned long long mm = s_msk[ww];
            if (mm) { nxt = (ww << 6) + __builtin_ctzll(mm); break; }
        }
    }
    __syncthreads();   // s_cs fully written

    bool valid = (!z) && (prev >= 0) && (nxt < DS);
    if (valid) {
        float cs_j   = s_cs[j];
        float cs_pm1 = (prev > 0) ? s_cs[prev - 1] : 0.f;
        float cs_n   = s_cs[nxt];
        float cs_jm1 = (j > 0) ? s_cs[j - 1] : 0.f;
        return (cs_j - cs_pm1) / (float)(j - prev + 1)
             + (cs_n - cs_jm1) / (float)(nxt - j + 1);
    }
    return 2.f * x;
}

// K_A: one downsampled row per block. Thread j loads the 16B chunk that
// CONTAINS sample j (byte 32j, elem 0) -> 2 loads/thread, no LDS exchange.
__global__ __launch_bounds__(256) void k_row(const float* __restrict__ x0,
                                             const int* __restrict__ x1,
                                             float2* __restrict__ xz,
                                             float* __restrict__ yH) {
    __shared__ float s_cs[DS];
    __shared__ unsigned long long s_msk[4];
    __shared__ float s_ws[4];
    const int j = threadIdx.x;
    const int line = blockIdx.x;            // n*256 + i
    const int n = line >> 8, i = line & 255;

    const float* rb0 = x0 + (size_t)(n * FULL + i * 8) * FULL;
    const int*   rb1 = x1 + (size_t)(n * FULL + i * 8) * FULL;
    f32x4 a = __builtin_nontemporal_load((const f32x4*)(rb0 + 8 * (size_t)j));
    i32x4 b = __builtin_nontemporal_load((const i32x4*)(rb1 + 8 * (size_t)j));
    float x = a[0];
    bool  z = (b[0] == 0);

    float r = seg_fast(x, z, j, s_cs, s_msk, s_ws);

    yH[(line << 8) + j] = r;                              // coalesced
    xz[(line << 8) + j] = make_float2(x, z ? 1.f : 0.f);  // coalesced
}

// K_B: (image, colgroup, row-half) per block — 1024 blocks. Identical to the
// 43.46us best config EXCEPT the output stores are nontemporal (32B/thread
// kept): test whether bypassing L2/L3 write-allocate recovers fill-rate BW.
__global__ __launch_bounds__(256) void k_colup(const float2* __restrict__ xz,
                                               const float* __restrict__ yH,
                                               f32x4* __restrict__ out) {
    __shared__ float s_x[CG][DS];
    __shared__ float s_z[CG][DS];
    __shared__ float s_out[CG][DS + 1];      // +1 pad: conflict-free col reads
    __shared__ float s_cs[DS];
    __shared__ unsigned long long s_msk[4];
    __shared__ float s_ws[4];
    const int t = threadIdx.x;               // downsampled row
    const int g = blockIdx.x;                // n*128 + rowhalf*64 + colgroup
    const int n  = g >> 7;
    const int q  = (g >> 6) & 1;             // which half of output rows
    const int c0 = (g & 63) * CG;

    const float2* base = xz + (n << 16) + (t << 8) + c0;
    f32x4 v0 = *(const f32x4*)(base);        // (x,z) for c0, c0+1
    f32x4 v1 = *(const f32x4*)(base + 2);    // (x,z) for c0+2, c0+3
    f32x4 h  = *(const f32x4*)(yH + (n << 16) + (t << 8) + c0);
    s_x[0][t] = v0[0]; s_z[0][t] = v0[1];
    s_x[1][t] = v0[2]; s_z[1][t] = v0[3];
    s_x[2][t] = v1[0]; s_z[2][t] = v1[1];
    s_x[3][t] = v1[2]; s_z[3][t] = v1[3];
    // no barrier needed: each thread reads back only its own s_x/s_z entries.

    #pragma unroll
    for (int c = 0; c < CG; ++c) {
        float x = s_x[c][t];
        bool  z = (s_z[c][t] != 0.f);
        float r = seg_fast(x, z, t, s_cs, s_msk, s_ws);
        s_out[c][t] = r + h[c];              // vertical + horizontal
    }
    __syncthreads();                         // s_out complete

    // This block's half: 1024 output rows x 8 f32x4 slots (32 cols).
    // Each thread: two consecutive f32x4 (32B) per iteration, NT stores.
    f32x4* ob = out + ((size_t)n << 20) + (c0 << 1);
    #pragma unroll 4
    for (int k = 0; k < 16; ++k) {
        int idx = (k << 8) + t;              // 0..4095 (pair index)
        int I   = (q << 10) + (idx >> 2);    // output row
        int c   = idx & 3;                   // downsampled column within group
        float v = s_out[c][I >> 3];
        f32x4 vv = { v, v, v, v };
        size_t o = (size_t)I * 512 + (c << 1);
        __builtin_nontemporal_store(vv, &ob[o]);
        __builtin_nontemporal_store(vv, &ob[o + 1]);
    }
}

extern "C" void kernel_launch(void* const* d_in, const int* in_sizes, int n_in,
                              void* d_out, int out_size, void* d_ws, size_t ws_size,
                              hipStream_t stream) {
    const float* x0 = (const float*)d_in[0];
    const int*   x1 = (const int*)d_in[1];
    f32x4* out = (f32x4*)d_out;

    // ws layout: xz (4MB float2) | yH (2MB)
    float2* xz = (float2*)d_ws;
    float*  yH = (float*)(xz + NIMG * DS * DS);

    dim3 blk(256);
    k_row  <<<dim3(NIMG * DS),          blk, 0, stream>>>(x0, x1, xz, yH);
    k_colup<<<dim3(2 * NIMG * DS / CG), blk, 0, stream>>>(xz, yH, out);
}

// Round 16
// 42.772 us; speedup vs baseline: 1.8212x; 1.8212x over previous
//
#include <hip/hip_runtime.h>

#define DS   256
#define FULL 2048
#define NIMG 8
#define CG   4      // columns per k_colup block

typedef float f32x4 __attribute__((ext_vector_type(4)));
typedef int   i32x4 __attribute__((ext_vector_type(4)));

// Segment-mean contribution for a 256-long line handled by 256 threads.
// Returns lr+rl (or 2x where invalid), matching the reference _seg_means.
// Safe to call back-to-back (internal barriers cover the reuse hazards).
__device__ __forceinline__ float seg_fast(float x, bool z, int j,
                                          float* s_cs,
                                          unsigned long long* s_msk,
                                          float* s_ws) {
    const int lane = j & 63;
    const int w    = j >> 6;
    unsigned long long m = __ballot(z);

    float s = x;
    #pragma unroll
    for (int off = 1; off < 64; off <<= 1) {
        float t = __shfl_up(s, off, 64);
        if (lane >= off) s += t;
    }
    if (lane == 63) s_ws[w]  = s;
    if (lane == 0)  s_msk[w] = m;
    __syncthreads();

    float pre = 0.f;
    for (int ww = 0; ww < w; ++ww) pre += s_ws[ww];
    s += pre;
    s_cs[j] = s;

    unsigned long long lo = m & ((1ULL << lane) - 1ULL);
    int prev = -1;
    if (lo) prev = (w << 6) + 63 - __builtin_clzll(lo);
    else {
        for (int ww = w - 1; ww >= 0; --ww) {
            unsigned long long mm = s_msk[ww];
            if (mm) { prev = (ww << 6) + 63 - __builtin_clzll(mm); break; }
        }
    }
    unsigned long long hi = m & ~((2ULL << lane) - 1ULL);
    int nxt = DS;
    if (hi) nxt = (w << 6) + __builtin_ctzll(hi);
    else {
        for (int ww = w + 1; ww < 4; ++ww) {
            unsigned long long mm = s_msk[ww];
            if (mm) { nxt = (ww << 6) + __builtin_ctzll(mm); break; }
        }
    }
    __syncthreads();   // s_cs fully written

    bool valid = (!z) && (prev >= 0) && (nxt < DS);
    if (valid) {
        float cs_j   = s_cs[j];
        float cs_pm1 = (prev > 0) ? s_cs[prev - 1] : 0.f;
        float cs_n   = s_cs[nxt];
        float cs_jm1 = (j > 0) ? s_cs[j - 1] : 0.f;
        return (cs_j - cs_pm1) / (float)(j - prev + 1)
             + (cs_n - cs_jm1) / (float)(nxt - j + 1);
    }
    return 2.f * x;
}

// K_A: one downsampled row per block. Thread j loads the 16B chunk that
// CONTAINS sample j (byte 32j, elem 0) -> 2 loads/thread. PLAIN loads
// (single-variable test: nt stores proved catastrophically slow on gfx950;
// isolating whether nt loads also take a slow path).
__global__ __launch_bounds__(256) void k_row(const float* __restrict__ x0,
                                             const int* __restrict__ x1,
                                             float2* __restrict__ xz,
                                             float* __restrict__ yH) {
    __shared__ float s_cs[DS];
    __shared__ unsigned long long s_msk[4];
    __shared__ float s_ws[4];
    const int j = threadIdx.x;
    const int line = blockIdx.x;            // n*256 + i
    const int n = line >> 8, i = line & 255;

    const float* rb0 = x0 + (size_t)(n * FULL + i * 8) * FULL;
    const int*   rb1 = x1 + (size_t)(n * FULL + i * 8) * FULL;
    f32x4 a = *(const f32x4*)(rb0 + 8 * (size_t)j);
    i32x4 b = *(const i32x4*)(rb1 + 8 * (size_t)j);
    float x = a[0];
    bool  z = (b[0] == 0);

    float r = seg_fast(x, z, j, s_cs, s_msk, s_ws);

    yH[(line << 8) + j] = r;                              // coalesced
    xz[(line << 8) + j] = make_float2(x, z ? 1.f : 0.f);  // coalesced
}

// K_B: (image, colgroup, row-half) per block — 1024 blocks. Byte-identical
// to the 43.46us best config (R10): LDS staging, plain 32B stores.
__global__ __launch_bounds__(256) void k_colup(const float2* __restrict__ xz,
                                               const float* __restrict__ yH,
                                               f32x4* __restrict__ out) {
    __shared__ float s_x[CG][DS];
    __shared__ float s_z[CG][DS];
    __shared__ float s_out[CG][DS + 1];      // +1 pad: conflict-free col reads
    __shared__ float s_cs[DS];
    __shared__ unsigned long long s_msk[4];
    __shared__ float s_ws[4];
    const int t = threadIdx.x;               // downsampled row
    const int g = blockIdx.x;                // n*128 + rowhalf*64 + colgroup
    const int n  = g >> 7;
    const int q  = (g >> 6) & 1;             // which half of output rows
    const int c0 = (g & 63) * CG;

    const float2* base = xz + (n << 16) + (t << 8) + c0;
    f32x4 v0 = *(const f32x4*)(base);        // (x,z) for c0, c0+1
    f32x4 v1 = *(const f32x4*)(base + 2);    // (x,z) for c0+2, c0+3
    f32x4 h  = *(const f32x4*)(yH + (n << 16) + (t << 8) + c0);
    s_x[0][t] = v0[0]; s_z[0][t] = v0[1];
    s_x[1][t] = v0[2]; s_z[1][t] = v0[3];
    s_x[2][t] = v1[0]; s_z[2][t] = v1[1];
    s_x[3][t] = v1[2]; s_z[3][t] = v1[3];
    // no barrier needed: each thread reads back only its own s_x/s_z entries.

    #pragma unroll
    for (int c = 0; c < CG; ++c) {
        float x = s_x[c][t];
        bool  z = (s_z[c][t] != 0.f);
        float r = seg_fast(x, z, t, s_cs, s_msk, s_ws);
        s_out[c][t] = r + h[c];              // vertical + horizontal
    }
    __syncthreads();                         // s_out complete

    // This block's half: 1024 output rows x 8 f32x4 slots (32 cols).
    // Each thread: two consecutive f32x4 (32B) per iteration, plain stores.
    f32x4* ob = out + ((size_t)n << 20) + (c0 << 1);
    #pragma unroll 4
    for (int k = 0; k < 16; ++k) {
        int idx = (k << 8) + t;              // 0..4095 (pair index)
        int I   = (q << 10) + (idx >> 2);    // output row
        int c   = idx & 3;                   // downsampled column within group
        float v = s_out[c][I >> 3];
        f32x4 vv = { v, v, v, v };
        size_t o = (size_t)I * 512 + (c << 1);
        ob[o]     = vv;
        ob[o + 1] = vv;
    }
}

extern "C" void kernel_launch(void* const* d_in, const int* in_sizes, int n_in,
                              void* d_out, int out_size, void* d_ws, size_t ws_size,
                              hipStream_t stream) {
    const float* x0 = (const float*)d_in[0];
    const int*   x1 = (const int*)d_in[1];
    f32x4* out = (f32x4*)d_out;

    // ws layout: xz (4MB float2) | yH (2MB)
    float2* xz = (float2*)d_ws;
    float*  yH = (float*)(xz + NIMG * DS * DS);

    dim3 blk(256);
    k_row  <<<dim3(NIMG * DS),          blk, 0, stream>>>(x0, x1, xz, yH);
    k_colup<<<dim3(2 * NIMG * DS / CG), blk, 0, stream>>>(xz, yH, out);
}